// Round 7
// baseline (907.779 us; speedup 1.0000x reference)
//
#include <hip/hip_runtime.h>
#include <hip/hip_bf16.h>
#include <hip/hip_fp16.h>
#include <math.h>

// T=1024 time steps, S=512 sequences, D=32 features, K=64 states (= wave width)
#define TT 1024
#define SS 512
#define DD 32
#define KK 64

#define LOG2PI_F 1.8378770664093453f

typedef float v2f __attribute__((ext_vector_type(2)));

__device__ __forceinline__ v2f fma2(v2f a, v2f b, v2f c) {
#if __has_builtin(__builtin_elementwise_fma)
    return __builtin_elementwise_fma(a, b, c);
#else
    v2f r; r.x = fmaf(a.x, b.x, c.x); r.y = fmaf(a.y, b.y, c.y); return r;
#endif
}

// ---------------------------------------------------------------------------
// FUSED forward pass: one wave per sequence; lane = state k.
// Round-3 recursion structure verbatim (311us, passed) + on-the-fly emission:
//  - emission for step t computed at the top of step t from x(t), which was
//    issued 2 steps earlier (2-slot double buffer; x addresses are
//    wave-uniform -> scalar-load path; ~1100cyc load-to-use covers HBM).
//  - the 96-VALU quad + 6-round shuffle-max run in parallel with the
//    alpha_sh ds_reads + dot chain (independent), filling round-3's stall
//    windows (VALUBusy was 13%).
//  - removes the separate emission kernel AND the 64MB fp16 pbuf round-trip;
//    p stays fp32 (better accuracy than rounds 2-6).
// Max-shift: p''(t) = exp(logp - mx_t); Sum_t mx_t (wave-uniform macc) folds
// into seq_logd. Normalize every 4th step: with max-shifted emissions the
// per-step den'' >= ~1e-5 so 4 raw steps stay >= ~1e-20 >> fp32 min.
// Single-wave block: wave_barrier() (0-instr scheduling fence) instead of
// __syncthreads() — no vmcnt(0) drain, prefetches stay in flight.
__global__ __launch_bounds__(64) void hmm_fused(
    const float* __restrict__ data,      // [T,S,D]
    const float* __restrict__ initial,   // [K]
    const float* __restrict__ trans,     // [K,K]
    const float* __restrict__ means,     // [K,D]
    const float* __restrict__ covars,    // [K,D]
    float* __restrict__ out_alpha,       // [S,K]
    float* __restrict__ seq_logd)        // [S]
{
    const int s = blockIdx.x;
    const int k = threadIdx.x;

    // A column k as packed pairs: acl[j] = (A[2j][k], A[2j+1][k])
    v2f acl[KK / 2];
#pragma unroll
    for (int j = 0; j < KK / 2; ++j) {
        acl[j].x = trans[(2 * j) * KK + k];
        acl[j].y = trans[(2 * j + 1) * KK + k];
    }

    // Gaussian params for state k
    float w[DD], m[DD];
    float c0 = DD * LOG2PI_F;
#pragma unroll
    for (int d = 0; d < DD; ++d) {
        float c = covars[k * DD + d];
        w[d] = 1.0f / c;
        m[d] = means[k * DD + d];
        c0 += __logf(c);
    }
    const float inik = initial[k];

    __shared__ __align__(16) float alpha_sh[KK];

    // x(t) lives at data + t*S*D + s*D; address is wave-uniform.
    const float* xbase = data + (size_t)s * DD;
    const size_t XST = (size_t)SS * DD;

    // 2-slot double buffer of x: slot t&1 holds x(t), refilled with x(t+2)
    float4 xb[2][DD / 4];
#pragma unroll
    for (int slot = 0; slot < 2; ++slot) {
        const float4* xp = (const float4*)(xbase + XST * (size_t)slot);
#pragma unroll
        for (int j = 0; j < DD / 4; ++j) xb[slot][j] = xp[j];
    }

    float logd = 0.0f, macc = 0.0f;
    float a = 0.0f;

    for (int t4 = 0; t4 < TT / 4; ++t4) {
#pragma unroll
        for (int u = 0; u < 4; ++u) {
            const int t = 4 * t4 + u;
            const int slot = u & 1;

            // ---- emission quad from xb[slot] (= x(t)) ----
            float q0 = 0.0f, q1 = 0.0f;
#pragma unroll
            for (int d4 = 0; d4 < DD / 4; ++d4) {
                float4 x = xb[slot][d4];
                float t0 = x.x - m[4*d4+0]; q0 = fmaf(w[4*d4+0] * t0, t0, q0);
                float t1 = x.y - m[4*d4+1]; q1 = fmaf(w[4*d4+1] * t1, t1, q1);
                float t2 = x.z - m[4*d4+2]; q0 = fmaf(w[4*d4+2] * t2, t2, q0);
                float t3 = x.w - m[4*d4+3]; q1 = fmaf(w[4*d4+3] * t3, t3, q1);
            }

            // ---- refill slot with x(t+2) (WAR handled by waitcnt; in
            // flight for ~1.5 steps before next use) ----
            {
                int tn = t + 2; if (tn >= TT) tn = TT - 1;   // harmless clamp
                const float4* xp = (const float4*)(xbase + XST * (size_t)tn);
#pragma unroll
                for (int j = 0; j < DD / 4; ++j) xb[slot][j] = xp[j];
            }

            const float logp = -0.5f * (q0 + q1 + c0);
            float mx = logp;
#pragma unroll
            for (int off = 32; off > 0; off >>= 1)
                mx = fmaxf(mx, __shfl_xor(mx, off, 64));
            const float p = __expf(logp - mx);
            macc += mx;                       // wave-uniform

            // ---- recursion (round-3 code) ----
            if (t == 0) {
                a = inik * p;
            } else {
                const float4* ash4 = (const float4*)alpha_sh;
                v2f a0 = {0,0}, a1 = {0,0}, a2 = {0,0}, a3 = {0,0};
#pragma unroll
                for (int j4 = 0; j4 < KK / 4; ++j4) {
                    float4 av = ash4[j4];
                    v2f lo; lo.x = av.x; lo.y = av.y;
                    v2f hi; hi.x = av.z; hi.y = av.w;
                    if (j4 & 1) {
                        a2 = fma2(lo, acl[2 * j4], a2);
                        a3 = fma2(hi, acl[2 * j4 + 1], a3);
                    } else {
                        a0 = fma2(lo, acl[2 * j4], a0);
                        a1 = fma2(hi, acl[2 * j4 + 1], a1);
                    }
                }
                v2f sv = (a0 + a1) + (a2 + a3);
                a = p * (sv.x + sv.y);
            }

            if (u == 3) {                      // t % 4 == 3: normalize + log
                float den = a;
#pragma unroll
                for (int off = 32; off > 0; off >>= 1)
                    den += __shfl_xor(den, off, 64);
                logd += __logf(den);
                a *= __builtin_amdgcn_rcpf(den);
            }

            alpha_sh[k] = a;
            __builtin_amdgcn_wave_barrier();   // order LDS write vs next reads
        }
    }

    out_alpha[(size_t)s * KK + k] = a;        // t=1023 ends on a normalize
    if (k == 0) seq_logd[s] = logd + macc;    // both wave-uniform
}

// ---------------------------------------------------------------------------
// nll = -sum_s seq_logd[s]
__global__ __launch_bounds__(256) void finalize(
    const float* __restrict__ seq_logd, float* __restrict__ out_nll)
{
    float v = 0.0f;
    for (int j = threadIdx.x; j < SS; j += 256) v += seq_logd[j];
#pragma unroll
    for (int off = 32; off > 0; off >>= 1)
        v += __shfl_xor(v, off, 64);
    __shared__ float sh[4];
    if ((threadIdx.x & 63) == 0) sh[threadIdx.x >> 6] = v;
    __syncthreads();
    if (threadIdx.x == 0) {
        double total = ((double)sh[0] + sh[1]) + ((double)sh[2] + sh[3]);
        out_nll[0] = (float)(-total);
    }
}

extern "C" void kernel_launch(void* const* d_in, const int* in_sizes, int n_in,
                              void* d_out, int out_size, void* d_ws, size_t ws_size,
                              hipStream_t stream) {
    const float* data    = (const float*)d_in[0];  // [T,S,D]
    const float* initial = (const float*)d_in[1];  // [K]
    const float* trans   = (const float*)d_in[2];  // [K,K]
    const float* means   = (const float*)d_in[3];  // [K,D]
    const float* covars  = (const float*)d_in[4];  // [K,D]

    float* out_alpha = (float*)d_out;                    // [S,K]
    float* out_nll   = (float*)d_out + (size_t)SS * KK;  // 1 float
    float* seq_logd  = (float*)d_ws;                     // [S]

    hmm_fused<<<SS, 64, 0, stream>>>(data, initial, trans, means, covars,
                                     out_alpha, seq_logd);
    finalize<<<1, 256, 0, stream>>>(seq_logd, out_nll);
}